// Round 1
// baseline (407.552 us; speedup 1.0000x reference)
//
#include <hip/hip_runtime.h>

// Problem constants (fixed by setup_inputs)
#define BB 2
#define TT 2048
#define CC 1024
#define HH 16
#define DD 64
#define KDIM 1024
#define MROWS (BB*TT)   // 4096

typedef __attribute__((ext_vector_type(8))) short  frag_b16;  // 8 bf16 (4 VGPRs)
typedef __attribute__((ext_vector_type(4))) float  f32x4;
typedef __attribute__((ext_vector_type(4))) unsigned short us4;

__device__ __forceinline__ unsigned short f2bf(float f) {
    unsigned int u = __builtin_bit_cast(unsigned int, f);
    u += 0x7FFFu + ((u >> 16) & 1u);   // RNE
    return (unsigned short)(u >> 16);
}

// ---------------------------------------------------------------- fp32 -> bf16
__global__ __launch_bounds__(256) void cvt4(const float* __restrict__ src,
                                            unsigned short* __restrict__ dst, int n) {
    int i = (blockIdx.x * 256 + threadIdx.x) * 4;
    if (i >= n) return;
    float4 f = *reinterpret_cast<const float4*>(src + i);
    us4 o;
    o.x = f2bf(f.x); o.y = f2bf(f.y); o.z = f2bf(f.z); o.w = f2bf(f.w);
    *reinterpret_cast<us4*>(dst + i) = o;
}

// ------------------------------------------------- QKV projection (+RoPE) GEMM
// out[n][o] = sum_c X[n][c] * W[o][c] + b[o]; both row-major -> both fragments
// are contiguous 16B row loads.
// A-frag: A[m=lane&15][k=quad*8+j]; B-frag: B[k=quad*8+j][n=lane&15] = W[n][k].
// C/D: col = lane&15 (o), row = quad*4+reg (n).
__global__ __launch_bounds__(256) void qkv_gemm_rope(
        const unsigned short* __restrict__ X,
        const unsigned short* __restrict__ Wq,
        const unsigned short* __restrict__ Wk,
        const unsigned short* __restrict__ Wv,
        const float* __restrict__ bq, const float* __restrict__ bk,
        const float* __restrict__ bv,
        unsigned short* __restrict__ Qo,   // [B,H,T,D] bf16 (roped)
        unsigned short* __restrict__ Ko,   // [B,H,T,D] bf16 (roped)
        unsigned short* __restrict__ VTo)  // [B,H,D,T] bf16
{
    const int z = blockIdx.z;
    const unsigned short* W = (z == 0) ? Wq : (z == 1) ? Wk : Wv;
    const float* bias = (z == 0) ? bq : (z == 1) ? bk : bv;

    const int wave = threadIdx.x >> 6;
    const int lane = threadIdx.x & 63;
    const int l16 = lane & 15;
    const int quad = lane >> 4;

    const int row0 = blockIdx.x * 128 + (wave >> 1) * 64;
    const int col0 = blockIdx.y * 128 + (wave & 1) * 64;

    f32x4 acc[4][4] = {};

    for (int kk = 0; kk < KDIM; kk += 32) {
        frag_b16 a[4], b[4];
#pragma unroll
        for (int r = 0; r < 4; ++r)
            a[r] = *reinterpret_cast<const frag_b16*>(
                X + (size_t)(row0 + r * 16 + l16) * KDIM + kk + quad * 8);
#pragma unroll
        for (int c = 0; c < 4; ++c)
            b[c] = *reinterpret_cast<const frag_b16*>(
                W + (size_t)(col0 + c * 16 + l16) * KDIM + kk + quad * 8);
#pragma unroll
        for (int r = 0; r < 4; ++r)
#pragma unroll
            for (int c = 0; c < 4; ++c)
                acc[r][c] = __builtin_amdgcn_mfma_f32_16x16x32_bf16(a[r], b[c], acc[r][c], 0, 0, 0);
    }

#pragma unroll
    for (int r = 0; r < 4; ++r) {
#pragma unroll
        for (int c = 0; c < 4; ++c) {
#pragma unroll
            for (int g = 0; g < 4; ++g) {
                int n = row0 + r * 16 + quad * 4 + g;
                int o = col0 + c * 16 + l16;
                float v = acc[r][c][g] + bias[o];
                int b_ = n >> 11;          // /T
                int t  = n & (TT - 1);
                int h  = o >> 6;
                int d  = o & (DD - 1);
                if (z == 2) {
                    VTo[(((size_t)(b_ * HH + h) * DD + d) * TT) + t] = f2bf(v);
                } else {
                    float pv = __shfl_xor(v, 1);
                    // angle = t / 10000^{(d&~1)/D}
                    float inv = __expf(-(float)(d & ~1) * (9.210340371976184f / (float)DD));
                    float ang = (float)t * inv;
                    float cs = cosf(ang);
                    float sn = sinf(ang);
                    float outv = (d & 1) ? (pv * sn + v * cs) : (v * cs - pv * sn);
                    unsigned short* dst = (z == 0) ? Qo : Ko;
                    dst[((size_t)(b_ * HH + h) * TT + t) * DD + d] = f2bf(outv);
                }
            }
        }
    }
}

// ------------------------------------------------------------ flash attention
// 1 wave per block; Q tile = 32 rows, K/V tile = 32 cols; online softmax.
__global__ __launch_bounds__(64) void attn(
        const unsigned short* __restrict__ Q,
        const unsigned short* __restrict__ K,
        const unsigned short* __restrict__ VT,
        unsigned short* __restrict__ Y)   // [B*T, C] bf16
{
    const int qt = blockIdx.x;     // 0..T/32-1
    const int bh = blockIdx.y;     // 0..B*H-1
    const int q0 = qt * 32;
    const int lane = threadIdx.x;
    const int l16 = lane & 15;
    const int quad = lane >> 4;

    const unsigned short* Qp = Q + (size_t)bh * TT * DD;
    const unsigned short* Kp = K + (size_t)bh * TT * DD;
    const unsigned short* Vp = VT + (size_t)bh * DD * TT;

    __shared__ __align__(64) unsigned short Plds[32][32];

    frag_b16 aq[2][2];
#pragma unroll
    for (int rt = 0; rt < 2; ++rt)
#pragma unroll
        for (int kc = 0; kc < 2; ++kc)
            aq[rt][kc] = *reinterpret_cast<const frag_b16*>(
                Qp + (size_t)(q0 + rt * 16 + l16) * DD + kc * 32 + quad * 8);

    f32x4 yacc[2][4] = {};
    float m[2][4], l[2][4];
#pragma unroll
    for (int rt = 0; rt < 2; ++rt)
#pragma unroll
        for (int g = 0; g < 4; ++g) { m[rt][g] = -INFINITY; l[rt][g] = 0.f; }

    for (int j0 = 0; j0 <= q0; j0 += 32) {
        frag_b16 bk[2][2];
#pragma unroll
        for (int ct = 0; ct < 2; ++ct)
#pragma unroll
            for (int kc = 0; kc < 2; ++kc)
                bk[ct][kc] = *reinterpret_cast<const frag_b16*>(
                    Kp + (size_t)(j0 + ct * 16 + l16) * DD + kc * 32 + quad * 8);

        f32x4 s[2][2] = {};
#pragma unroll
        for (int rt = 0; rt < 2; ++rt)
#pragma unroll
            for (int ct = 0; ct < 2; ++ct) {
                s[rt][ct] = __builtin_amdgcn_mfma_f32_16x16x32_bf16(aq[rt][0], bk[ct][0], s[rt][ct], 0, 0, 0);
                s[rt][ct] = __builtin_amdgcn_mfma_f32_16x16x32_bf16(aq[rt][1], bk[ct][1], s[rt][ct], 0, 0, 0);
            }

        float p[2][2][4];
        float rmax[2][4];
#pragma unroll
        for (int rt = 0; rt < 2; ++rt)
#pragma unroll
            for (int g = 0; g < 4; ++g) rmax[rt][g] = -INFINITY;

#pragma unroll
        for (int rt = 0; rt < 2; ++rt)
#pragma unroll
            for (int ct = 0; ct < 2; ++ct)
#pragma unroll
                for (int g = 0; g < 4; ++g) {
                    int rq = q0 + rt * 16 + quad * 4 + g;
                    int cj = j0 + ct * 16 + l16;
                    float v = s[rt][ct][g] * 0.125f;
                    if (cj > rq) v = -1e30f;
                    p[rt][ct][g] = v;
                    rmax[rt][g] = fmaxf(rmax[rt][g], v);
                }
        // row-max across the 16-lane column group
#pragma unroll
        for (int rt = 0; rt < 2; ++rt)
#pragma unroll
            for (int g = 0; g < 4; ++g) {
#pragma unroll
                for (int off = 1; off < 16; off <<= 1)
                    rmax[rt][g] = fmaxf(rmax[rt][g], __shfl_xor(rmax[rt][g], off));
            }

        float alpha[2][4];
#pragma unroll
        for (int rt = 0; rt < 2; ++rt)
#pragma unroll
            for (int g = 0; g < 4; ++g) {
                float mn = fmaxf(m[rt][g], rmax[rt][g]);
                alpha[rt][g] = __expf(m[rt][g] - mn);
                m[rt][g] = mn;
            }

        float rsum[2][4] = {};
#pragma unroll
        for (int rt = 0; rt < 2; ++rt)
#pragma unroll
            for (int ct = 0; ct < 2; ++ct)
#pragma unroll
                for (int g = 0; g < 4; ++g) {
                    float e = __expf(p[rt][ct][g] - m[rt][g]);
                    p[rt][ct][g] = e;
                    rsum[rt][g] += e;
                }
#pragma unroll
        for (int rt = 0; rt < 2; ++rt)
#pragma unroll
            for (int g = 0; g < 4; ++g) {
#pragma unroll
                for (int off = 1; off < 16; off <<= 1)
                    rsum[rt][g] += __shfl_xor(rsum[rt][g], off);
                l[rt][g] = l[rt][g] * alpha[rt][g] + rsum[rt][g];
            }

        __syncthreads();   // protect previous iteration's P reads
#pragma unroll
        for (int rt = 0; rt < 2; ++rt)
#pragma unroll
            for (int ct = 0; ct < 2; ++ct)
#pragma unroll
                for (int g = 0; g < 4; ++g)
                    Plds[rt * 16 + quad * 4 + g][ct * 16 + l16] = f2bf(p[rt][ct][g]);
        __syncthreads();

        frag_b16 pa[2];
#pragma unroll
        for (int rt = 0; rt < 2; ++rt)
            pa[rt] = *reinterpret_cast<const frag_b16*>(&Plds[rt * 16 + l16][quad * 8]);

        frag_b16 bv[4];
#pragma unroll
        for (int dt = 0; dt < 4; ++dt)
            bv[dt] = *reinterpret_cast<const frag_b16*>(
                Vp + (size_t)(dt * 16 + l16) * TT + j0 + quad * 8);

#pragma unroll
        for (int rt = 0; rt < 2; ++rt)
#pragma unroll
            for (int dt = 0; dt < 4; ++dt) {
#pragma unroll
                for (int g = 0; g < 4; ++g) yacc[rt][dt][g] *= alpha[rt][g];
                yacc[rt][dt] = __builtin_amdgcn_mfma_f32_16x16x32_bf16(pa[rt], bv[dt], yacc[rt][dt], 0, 0, 0);
            }
    }

    const int b_ = bh >> 4, h = bh & (HH - 1);
#pragma unroll
    for (int rt = 0; rt < 2; ++rt)
#pragma unroll
        for (int dt = 0; dt < 4; ++dt)
#pragma unroll
            for (int g = 0; g < 4; ++g) {
                int trow = q0 + rt * 16 + quad * 4 + g;
                int d = dt * 16 + l16;
                float v = yacc[rt][dt][g] / l[rt][g];
                Y[((size_t)(b_ * TT + trow)) * CC + h * DD + d] = f2bf(v);
            }
}

// --------------------------------------------------------- output projection
__global__ __launch_bounds__(256) void out_gemm(
        const unsigned short* __restrict__ Y,
        const unsigned short* __restrict__ Wo,
        const float* __restrict__ bo,
        float* __restrict__ out)
{
    const int wave = threadIdx.x >> 6;
    const int lane = threadIdx.x & 63;
    const int l16 = lane & 15;
    const int quad = lane >> 4;

    const int row0 = blockIdx.x * 128 + (wave >> 1) * 64;
    const int col0 = blockIdx.y * 128 + (wave & 1) * 64;

    f32x4 acc[4][4] = {};

    for (int kk = 0; kk < KDIM; kk += 32) {
        frag_b16 a[4], b[4];
#pragma unroll
        for (int r = 0; r < 4; ++r)
            a[r] = *reinterpret_cast<const frag_b16*>(
                Y + (size_t)(row0 + r * 16 + l16) * KDIM + kk + quad * 8);
#pragma unroll
        for (int c = 0; c < 4; ++c)
            b[c] = *reinterpret_cast<const frag_b16*>(
                Wo + (size_t)(col0 + c * 16 + l16) * KDIM + kk + quad * 8);
#pragma unroll
        for (int r = 0; r < 4; ++r)
#pragma unroll
            for (int c = 0; c < 4; ++c)
                acc[r][c] = __builtin_amdgcn_mfma_f32_16x16x32_bf16(a[r], b[c], acc[r][c], 0, 0, 0);
    }

#pragma unroll
    for (int r = 0; r < 4; ++r)
#pragma unroll
        for (int c = 0; c < 4; ++c)
#pragma unroll
            for (int g = 0; g < 4; ++g) {
                int n = row0 + r * 16 + quad * 4 + g;
                int o = col0 + c * 16 + l16;
                out[(size_t)n * CC + o] = acc[r][c][g] + bo[o];
            }
}

// ---------------------------------------------------------------------- launch
extern "C" void kernel_launch(void* const* d_in, const int* in_sizes, int n_in,
                              void* d_out, int out_size, void* d_ws, size_t ws_size,
                              hipStream_t stream) {
    const float* x  = (const float*)d_in[0];
    const float* Wq = (const float*)d_in[1];
    const float* bq = (const float*)d_in[2];
    const float* Wk = (const float*)d_in[3];
    const float* bk = (const float*)d_in[4];
    const float* Wv = (const float*)d_in[5];
    const float* bv = (const float*)d_in[6];
    const float* Wo = (const float*)d_in[7];
    const float* bo = (const float*)d_in[8];
    float* out = (float*)d_out;

    unsigned short* ws = (unsigned short*)d_ws;
    const size_t NX = (size_t)MROWS * CC;      // 4194304
    const size_t NW = (size_t)CC * CC;         // 1048576
    unsigned short* xb  = ws;
    unsigned short* wqb = xb  + NX;
    unsigned short* wkb = wqb + NW;
    unsigned short* wvb = wkb + NW;
    unsigned short* wob = wvb + NW;
    unsigned short* Qr  = wob + NW;
    unsigned short* Kr  = Qr  + NX;
    unsigned short* VTb = Kr  + NX;
    unsigned short* Yb  = VTb + NX;
    // total = 4*NX + 4*NW + NX = ~25.2M ushorts = ~48 MB of d_ws

    cvt4<<<dim3((unsigned)(NX / 1024)), 256, 0, stream>>>(x,  xb,  (int)NX);
    cvt4<<<dim3((unsigned)(NW / 1024)), 256, 0, stream>>>(Wq, wqb, (int)NW);
    cvt4<<<dim3((unsigned)(NW / 1024)), 256, 0, stream>>>(Wk, wkb, (int)NW);
    cvt4<<<dim3((unsigned)(NW / 1024)), 256, 0, stream>>>(Wv, wvb, (int)NW);
    cvt4<<<dim3((unsigned)(NW / 1024)), 256, 0, stream>>>(Wo, wob, (int)NW);

    qkv_gemm_rope<<<dim3(MROWS / 128, CC / 128, 3), 256, 0, stream>>>(
        xb, wqb, wkb, wvb, bq, bk, bv, Qr, Kr, VTb);

    attn<<<dim3(TT / 32, BB * HH), 64, 0, stream>>>(Qr, Kr, VTb, Yb);

    out_gemm<<<dim3(MROWS / 128, CC / 128), 256, 0, stream>>>(Yb, wob, bo, out);
}